// Round 6
// baseline (757.658 us; speedup 1.0000x reference)
//
#include <hip/hip_runtime.h>
#include <hip/hip_bf16.h>

typedef unsigned short u16;
typedef __attribute__((ext_vector_type(8))) short short8;
typedef __attribute__((ext_vector_type(4))) float f32x4;

#define NN   100000
#define NE   1600000
#define DIN  512
#define DHID 128
#define DOUT 40
#define NB   98          // ceil(NN / 1024) scan blocks

__device__ __forceinline__ float bf2f(u16 u) {
  union { unsigned int i; float f; } v; v.i = ((unsigned int)u) << 16; return v.f;
}
__device__ __forceinline__ u16 f2bf(float f) {
  __hip_bfloat16 h = __float2bfloat16(f);
  return *reinterpret_cast<u16*>(&h);
}

// ---------------- graph build ----------------
// dtypes (HW-verified rounds 1-4): ei int32, x/W1/b1/W2/b2 fp32, d_out fp32.

__global__ __launch_bounds__(256) void k_count(const int* __restrict__ ei, int* __restrict__ cnt) {
  int e = blockIdx.x * 256 + threadIdx.x;      // grid sized exactly NE/256
  int d = ei[NE + e];
  atomicAdd(&cnt[d], 1);
}

__global__ __launch_bounds__(256) void k_dinv(const int* __restrict__ cnt, float* __restrict__ dinv) {
  int i = blockIdx.x * 256 + threadIdx.x;
  if (i < NN) dinv[i] = rsqrtf((float)(cnt[i] + 1));   // +1 self-loop, always > 0
}

__global__ __launch_bounds__(256) void k_blocksum(const int* __restrict__ cnt, int* __restrict__ bsum) {
  __shared__ int s[256];
  int b = blockIdx.x, t = threadIdx.x;
  int base = b * 1024 + t * 4;
  int tot = 0;
  if (base < NN) { int4 v = *(const int4*)&cnt[base]; tot = v.x + v.y + v.z + v.w; }
  s[t] = tot; __syncthreads();
  for (int o = 128; o > 0; o >>= 1) { if (t < o) s[t] += s[t + o]; __syncthreads(); }
  if (t == 0) bsum[b] = s[0];
}

__global__ __launch_bounds__(128) void k_scanbsum(int* __restrict__ bsum) {
  __shared__ int s[128];
  int t = threadIdx.x;
  int v = (t < NB) ? bsum[t] : 0;
  s[t] = v; __syncthreads();
  for (int o = 1; o < 128; o <<= 1) {
    int add = (t >= o) ? s[t - o] : 0;
    __syncthreads();
    s[t] += add;
    __syncthreads();
  }
  if (t < NB) bsum[t] = s[t] - v;   // exclusive scan of block totals
}

__global__ __launch_bounds__(256) void k_scan3(const int* __restrict__ cnt, const int* __restrict__ bsum,
                                               int* __restrict__ offs) {
  __shared__ int s[256];
  int b = blockIdx.x, t = threadIdx.x;
  int base = b * 1024 + t * 4;
  int4 v = make_int4(0, 0, 0, 0);
  if (base < NN) v = *(const int4*)&cnt[base];
  int tot = v.x + v.y + v.z + v.w;
  s[t] = tot; __syncthreads();
  for (int o = 1; o < 256; o <<= 1) {
    int add = (t >= o) ? s[t - o] : 0;
    __syncthreads();
    s[t] += add;
    __syncthreads();
  }
  int tp = s[t] - tot;              // exclusive prefix of thread totals
  int b0 = bsum[b] + tp;
  if (base < NN) {
    int4 o4;
    o4.x = b0;
    o4.y = b0 + v.x;
    o4.z = b0 + v.x + v.y;
    o4.w = b0 + v.x + v.y + v.z;
    *(int4*)&offs[base] = o4;
  }
  if (b == 0 && t == 0) offs[NN] = NE;
}

__global__ __launch_bounds__(256) void k_scatter(const int* __restrict__ ei, const int* __restrict__ offs,
                                                 int* __restrict__ cursor, const float* __restrict__ dinv,
                                                 int* __restrict__ csr, float* __restrict__ wgt) {
  int e = blockIdx.x * 256 + threadIdx.x;
  int srcv = ei[e];
  int d = ei[NE + e];
  int pos = offs[d] + atomicAdd(&cursor[d], 1);
  csr[pos] = srcv;
  wgt[pos] = dinv[srcv];            // precomputed edge weight: dinv[src]
}

// ---------------- W1 -> bf16, transposed: wt[n][k] = bf16(W1[k][n]) ----------------

__global__ __launch_bounds__(256) void k_prepw(const float* __restrict__ W1, u16* __restrict__ wt) {
  int id = blockIdx.x * 256 + threadIdx.x;     // 65536 = 128 * 512
  int k = id & 511, n = id >> 9;
  wt[n * DIN + k] = f2bf(W1[k * DHID + n]);
}

// ---------------- GEMM1 (MFMA): h1[NN][128] = x[NN][512] @ W1[512][128], bf16 out -------
// Block: 64 rows x 128 cols, 256 thr = 4 waves; wave w -> rows w*16..w*16+15, all 8 n-tiles.
// mfma_f32_16x16x32_bf16: A[m=lane&15][k=(lane>>4)*8+j], B[n=lane&15][k=(lane>>4)*8+j],
// C/D: col=lane&15, row=(lane>>4)*4+reg  (guide-verified m89/m91).

__global__ __launch_bounds__(256) void k_gemm1(const float* __restrict__ x, const u16* __restrict__ wt,
                                               u16* __restrict__ h1) {
  __shared__ u16 xs[64][72];        // 64 rows x 64-K bf16, row stride 144B   (9.2 KB)
  __shared__ u16 ws[128][72];       // 128 cols x 64-K bf16 (B^T layout)      (18.4 KB)
  int t = threadIdx.x;
  int row0 = blockIdx.x * 64;
  int w = t >> 6, l = t & 63;
  int lm = l & 15, lq = l >> 4;     // col-in-tile / quad
  int mbase = w * 16;
  f32x4 acc[8];
#pragma unroll
  for (int nt = 0; nt < 8; nt++) acc[nt] = (f32x4){0.f, 0.f, 0.f, 0.f};

  for (int c = 0; c < 8; c++) {
    int k0 = c * 64;
    // stage x tile: 64 rows x 64 K, fp32 -> bf16 (1024 float4 units)
#pragma unroll
    for (int it = 0; it < 4; it++) {
      int u = t + it * 256;
      int row = u >> 4, seg = u & 15;
      int gr = row0 + row;
      float4 v = make_float4(0.f, 0.f, 0.f, 0.f);
      if (gr < NN) v = *(const float4*)&x[gr * DIN + k0 + seg * 4];
      ushort4 o;
      o.x = f2bf(v.x); o.y = f2bf(v.y); o.z = f2bf(v.z); o.w = f2bf(v.w);
      *(ushort4*)&xs[row][seg * 4] = o;
    }
    // stage W^T tile: 128 cols x 64 K bf16 (1024 x 16B units, contiguous copies)
#pragma unroll
    for (int it = 0; it < 4; it++) {
      int u = t + it * 256;
      int n = u >> 3, seg = u & 7;
      *(uint4*)&ws[n][seg * 8] = *(const uint4*)&wt[n * DIN + k0 + seg * 8];
    }
    __syncthreads();
#pragma unroll
    for (int s = 0; s < 2; s++) {
      short8 a = *(const short8*)&xs[mbase + lm][s * 32 + lq * 8];
#pragma unroll
      for (int nt = 0; nt < 8; nt++) {
        short8 b = *(const short8*)&ws[nt * 16 + lm][s * 32 + lq * 8];
        acc[nt] = __builtin_amdgcn_mfma_f32_16x16x32_bf16(a, b, acc[nt], 0, 0, 0);
      }
    }
    __syncthreads();
  }
  // epilogue: lane holds (row = lq*4+reg, col = lm) of each 16x16 tile
#pragma unroll
  for (int reg = 0; reg < 4; reg++) {
    int gr = row0 + mbase + lq * 4 + reg;
    if (gr < NN) {
#pragma unroll
      for (int nt = 0; nt < 8; nt++) {
        h1[gr * DHID + nt * 16 + lm] = f2bf(acc[nt][reg]);
      }
    }
  }
}

// ---------------- prop1: g = relu(b1 + Ahat @ h1), bf16 intermediate ----------------
// One 64-lane wave per node. Halves (lanes 0-31 / 32-63) process alternating edges;
// each lane covers 4 features via ushort4 (32 lanes x 8B = full 128-feat row per edge).
// Two edges in flight per half for ILP; shfl_xor(32) combines halves at the end.

__global__ __launch_bounds__(64) void k_prop1(const u16* __restrict__ h1, const float* __restrict__ dinv,
                                              const int* __restrict__ offs, const int* __restrict__ csr,
                                              const float* __restrict__ wgt, const float* __restrict__ b1,
                                              u16* __restrict__ g) {
  int n = blockIdx.x;
  int l = threadIdx.x;
  int half = l >> 5, c = l & 31;
  int fb = c * 4;
  float dn = dinv[n];
  float ax = 0.f, ay = 0.f, az = 0.f, aw = 0.f;
  if (half == 0) {                      // self-loop: dn * h1[n] (outer dn applied at end)
    ushort4 sv = *(const ushort4*)&h1[n * DHID + fb];
    ax = dn * bf2f(sv.x); ay = dn * bf2f(sv.y); az = dn * bf2f(sv.z); aw = dn * bf2f(sv.w);
  }
  int p1e = offs[n + 1];
  int q = offs[n] + half;
  for (; q + 2 < p1e; q += 4) {         // this half handles q and q+2
    int s0 = csr[q], s1 = csr[q + 2];
    float w0 = wgt[q], w1 = wgt[q + 2];
    ushort4 v0 = *(const ushort4*)&h1[s0 * DHID + fb];
    ushort4 v1 = *(const ushort4*)&h1[s1 * DHID + fb];
    ax += w0 * bf2f(v0.x) + w1 * bf2f(v1.x);
    ay += w0 * bf2f(v0.y) + w1 * bf2f(v1.y);
    az += w0 * bf2f(v0.z) + w1 * bf2f(v1.z);
    aw += w0 * bf2f(v0.w) + w1 * bf2f(v1.w);
  }
  if (q < p1e) {                        // tail (at most one more per half)
    int s0 = csr[q];
    float w0 = wgt[q];
    ushort4 v0 = *(const ushort4*)&h1[s0 * DHID + fb];
    ax += w0 * bf2f(v0.x); ay += w0 * bf2f(v0.y);
    az += w0 * bf2f(v0.z); aw += w0 * bf2f(v0.w);
  }
  ax += __shfl_xor(ax, 32); ay += __shfl_xor(ay, 32);
  az += __shfl_xor(az, 32); aw += __shfl_xor(aw, 32);
  if (half == 0) {
    float4 bv = *(const float4*)&b1[fb];
    ushort4 o;
    o.x = f2bf(fmaxf(bv.x + dn * ax, 0.f));
    o.y = f2bf(fmaxf(bv.y + dn * ay, 0.f));
    o.z = f2bf(fmaxf(bv.z + dn * az, 0.f));
    o.w = f2bf(fmaxf(bv.w + dn * aw, 0.f));
    *(ushort4*)&g[n * DHID + fb] = o;
  }
}

// ---------------- GEMM2: h2[NN][40] = g[NN][128] @ W2[128][40] ----------------

__global__ __launch_bounds__(320) void k_gemm2(const u16* __restrict__ g, const float* __restrict__ W2,
                                               u16* __restrict__ h2) {
  __shared__ float w2s[DHID][DOUT];   // 20 KB
  __shared__ float gs[8][DHID];       // 4 KB
  int t = threadIdx.x;
  int row0 = blockIdx.x * 8;
  for (int idx = t; idx < DHID * DOUT; idx += 320) ((float*)w2s)[idx] = W2[idx];
  for (int idx = t; idx < 8 * DHID; idx += 320) {
    int r = idx >> 7, k = idx & 127;
    int gr = row0 + r;
    ((float*)gs)[idx] = (gr < NN) ? bf2f(g[gr * DHID + k]) : 0.f;
  }
  __syncthreads();
  int r = t / DOUT, c = t % DOUT;     // 8 rows x 40 cols = 320 threads exactly
  float acc = 0.f;
#pragma unroll
  for (int k = 0; k < DHID; k += 4) {
    float4 gv = *(const float4*)&gs[r][k];
    acc += gv.x * w2s[k][c] + gv.y * w2s[k + 1][c] + gv.z * w2s[k + 2][c] + gv.w * w2s[k + 3][c];
  }
  int gr = row0 + r;
  if (gr < NN) h2[gr * DOUT + c] = f2bf(acc);
}

// ---------------- prop2 + log_softmax, fp32 out ----------------

__global__ __launch_bounds__(64) void k_prop2(const u16* __restrict__ h2, const float* __restrict__ dinv,
                                              const int* __restrict__ offs, const int* __restrict__ csr,
                                              const float* __restrict__ wgt, const float* __restrict__ b2,
                                              float* __restrict__ out) {
  int n = blockIdx.x, c = threadIdx.x;
  bool act = c < DOUT;
  float dn = dinv[n];
  float accE = 0.f;
  float self = act ? (dn * bf2f(h2[n * DOUT + c])) : 0.f;
  int p = offs[n], p1 = offs[n + 1];
  for (; p + 4 <= p1; p += 4) {
    int s0 = csr[p], s1 = csr[p + 1], s2 = csr[p + 2], s3 = csr[p + 3];
    float w0 = wgt[p], w1 = wgt[p + 1], w2 = wgt[p + 2], w3 = wgt[p + 3];
    float v0 = act ? bf2f(h2[s0 * DOUT + c]) : 0.f;
    float v1 = act ? bf2f(h2[s1 * DOUT + c]) : 0.f;
    float v2 = act ? bf2f(h2[s2 * DOUT + c]) : 0.f;
    float v3 = act ? bf2f(h2[s3 * DOUT + c]) : 0.f;
    accE += w0 * v0 + w1 * v1 + w2 * v2 + w3 * v3;
  }
  for (; p < p1; p++) {
    int s0 = csr[p];
    float v0 = act ? bf2f(h2[s0 * DOUT + c]) : 0.f;
    accE += wgt[p] * v0;
  }
  float logit = act ? (b2[c] + dn * (self + accE)) : -INFINITY;
  float mx = logit;
#pragma unroll
  for (int o = 32; o > 0; o >>= 1) mx = fmaxf(mx, __shfl_xor(mx, o));
  float pv = act ? __expf(logit - mx) : 0.f;
  float sm = pv;
#pragma unroll
  for (int o = 32; o > 0; o >>= 1) sm += __shfl_xor(sm, o);
  if (act) out[n * DOUT + c] = logit - mx - logf(sm);
}

// ---------------- launch ----------------

extern "C" void kernel_launch(void* const* d_in, const int* in_sizes, int n_in,
                              void* d_out, int out_size, void* d_ws, size_t ws_size,
                              hipStream_t stream) {
  const float* x  = (const float*)d_in[0];   // fp32
  const int* ei   = (const int*)d_in[1];     // int32 on device
  const float* W1 = (const float*)d_in[2];
  const float* b1 = (const float*)d_in[3];
  const float* W2 = (const float*)d_in[4];
  const float* b2 = (const float*)d_in[5];
  float* out      = (float*)d_out;           // fp32 output

  char* ws = (char*)d_ws;
  // layout (bytes): cnt 400000 | cursor 400000 | dinv 400000 | offs 400128 | bsum 512 | csr 6400000 |
  //                 h1 25600000 (h2 overlays h1) | g 25600000 | wt 131072 | wgt 6400000 -> ~65.7 MB
  int*   cnt    = (int*)(ws + 0);
  int*   cursor = (int*)(ws + 400000);
  float* dinv   = (float*)(ws + 800000);
  int*   offs   = (int*)(ws + 1200000);
  int*   bsum   = (int*)(ws + 1600128);
  int*   csr    = (int*)(ws + 1600640);
  u16*   h1     = (u16*)(ws + 8000640);
  u16*   g      = (u16*)(ws + 33600640);
  u16*   h2     = (u16*)(ws + 8000640);      // overlay on h1
  u16*   wt     = (u16*)(ws + 59200640);     // W1^T in bf16: [128][512]
  float* wgt    = (float*)(ws + 59331712);   // per-CSR-slot edge weight dinv[src]

  hipMemsetAsync(ws, 0, 800000, stream);                     // cnt + cursor = 0

  k_count   <<<NE / 256, 256, 0, stream>>>(ei, cnt);
  k_dinv    <<<(NN + 255) / 256, 256, 0, stream>>>(cnt, dinv);
  k_blocksum<<<NB, 256, 0, stream>>>(cnt, bsum);
  k_scanbsum<<<1, 128, 0, stream>>>(bsum);
  k_scan3   <<<NB, 256, 0, stream>>>(cnt, bsum, offs);
  k_scatter <<<NE / 256, 256, 0, stream>>>(ei, offs, cursor, dinv, csr, wgt);

  k_prepw   <<<(DIN * DHID) / 256, 256, 0, stream>>>(W1, wt);
  k_gemm1   <<<(NN + 63) / 64, 256, 0, stream>>>(x, wt, h1);
  k_prop1   <<<NN, 64, 0, stream>>>(h1, dinv, offs, csr, wgt, b1, g);
  k_gemm2   <<<(NN + 7) / 8, 320, 0, stream>>>(g, W2, h2);
  k_prop2   <<<NN, 64, 0, stream>>>(h2, dinv, offs, csr, wgt, b2, out);
}

// Round 7
// 711.848 us; speedup vs baseline: 1.0644x; 1.0644x over previous
//
#include <hip/hip_runtime.h>
#include <hip/hip_bf16.h>

typedef unsigned short u16;
typedef __attribute__((ext_vector_type(8))) short short8;
typedef __attribute__((ext_vector_type(4))) float f32x4;

#define NN   100000
#define NE   1600000
#define DIN  512
#define DHID 128
#define DOUT 40
#define NB   98          // ceil(NN / 1024) scan blocks

__device__ __forceinline__ float bf2f(u16 u) {
  union { unsigned int i; float f; } v; v.i = ((unsigned int)u) << 16; return v.f;
}
__device__ __forceinline__ u16 f2bf(float f) {
  __hip_bfloat16 h = __float2bfloat16(f);
  return *reinterpret_cast<u16*>(&h);
}

// ---------------- graph build ----------------
// dtypes (HW-verified rounds 1-4): ei int32, x/W1/b1/W2/b2 fp32, d_out fp32.
// CSR bucket order is irrelevant (we only sum over edges), so the count pass's
// atomicAdd return value doubles as the within-bucket ticket -> scatter needs no atomics.

__global__ __launch_bounds__(256) void k_count(const int* __restrict__ ei, int* __restrict__ cnt,
                                               int* __restrict__ ticket) {
  int base = (blockIdx.x * 256 + threadIdx.x) * 4;
  if (base >= NE) return;
  int4 d4 = *(const int4*)&ei[NE + base];
  int t0 = atomicAdd(&cnt[d4.x], 1);    // 4 independent atomics in flight
  int t1 = atomicAdd(&cnt[d4.y], 1);
  int t2 = atomicAdd(&cnt[d4.z], 1);
  int t3 = atomicAdd(&cnt[d4.w], 1);
  *(int4*)&ticket[base] = make_int4(t0, t1, t2, t3);
}

__global__ __launch_bounds__(256) void k_dinv(const int* __restrict__ cnt, float* __restrict__ dinv) {
  int i = blockIdx.x * 256 + threadIdx.x;
  if (i < NN) dinv[i] = rsqrtf((float)(cnt[i] + 1));   // +1 self-loop, always > 0
}

__global__ __launch_bounds__(256) void k_blocksum(const int* __restrict__ cnt, int* __restrict__ bsum) {
  __shared__ int s[256];
  int b = blockIdx.x, t = threadIdx.x;
  int base = b * 1024 + t * 4;
  int tot = 0;
  if (base < NN) { int4 v = *(const int4*)&cnt[base]; tot = v.x + v.y + v.z + v.w; }
  s[t] = tot; __syncthreads();
  for (int o = 128; o > 0; o >>= 1) { if (t < o) s[t] += s[t + o]; __syncthreads(); }
  if (t == 0) bsum[b] = s[0];
}

__global__ __launch_bounds__(128) void k_scanbsum(int* __restrict__ bsum) {
  __shared__ int s[128];
  int t = threadIdx.x;
  int v = (t < NB) ? bsum[t] : 0;
  s[t] = v; __syncthreads();
  for (int o = 1; o < 128; o <<= 1) {
    int add = (t >= o) ? s[t - o] : 0;
    __syncthreads();
    s[t] += add;
    __syncthreads();
  }
  if (t < NB) bsum[t] = s[t] - v;   // exclusive scan of block totals
}

__global__ __launch_bounds__(256) void k_scan3(const int* __restrict__ cnt, const int* __restrict__ bsum,
                                               int* __restrict__ offs) {
  __shared__ int s[256];
  int b = blockIdx.x, t = threadIdx.x;
  int base = b * 1024 + t * 4;
  int4 v = make_int4(0, 0, 0, 0);
  if (base < NN) v = *(const int4*)&cnt[base];
  int tot = v.x + v.y + v.z + v.w;
  s[t] = tot; __syncthreads();
  for (int o = 1; o < 256; o <<= 1) {
    int add = (t >= o) ? s[t - o] : 0;
    __syncthreads();
    s[t] += add;
    __syncthreads();
  }
  int tp = s[t] - tot;              // exclusive prefix of thread totals
  int b0 = bsum[b] + tp;
  if (base < NN) {
    int4 o4;
    o4.x = b0;
    o4.y = b0 + v.x;
    o4.z = b0 + v.x + v.y;
    o4.w = b0 + v.x + v.y + v.z;
    *(int4*)&offs[base] = o4;
  }
  if (b == 0 && t == 0) offs[NN] = NE;
}

__global__ __launch_bounds__(256) void k_scatter(const int* __restrict__ ei, const int* __restrict__ offs,
                                                 const int* __restrict__ ticket, const float* __restrict__ dinv,
                                                 int* __restrict__ csr, float* __restrict__ wgt) {
  int base = (blockIdx.x * 256 + threadIdx.x) * 4;
  if (base >= NE) return;
  int4 s4 = *(const int4*)&ei[base];
  int4 d4 = *(const int4*)&ei[NE + base];
  int4 t4 = *(const int4*)&ticket[base];
  int p0 = offs[d4.x] + t4.x;
  int p1 = offs[d4.y] + t4.y;
  int p2 = offs[d4.z] + t4.z;
  int p3 = offs[d4.w] + t4.w;
  csr[p0] = s4.x; wgt[p0] = dinv[s4.x];
  csr[p1] = s4.y; wgt[p1] = dinv[s4.y];
  csr[p2] = s4.z; wgt[p2] = dinv[s4.z];
  csr[p3] = s4.w; wgt[p3] = dinv[s4.w];
}

// ---------------- W1 -> bf16, transposed: wt[n][k] = bf16(W1[k][n]) ----------------

__global__ __launch_bounds__(256) void k_prepw(const float* __restrict__ W1, u16* __restrict__ wt) {
  int id = blockIdx.x * 256 + threadIdx.x;     // 65536 = 128 * 512
  int k = id & 511, n = id >> 9;
  wt[n * DIN + k] = f2bf(W1[k * DHID + n]);
}

// ---------------- GEMM1 (MFMA): h1[NN][128] = x[NN][512] @ W1[512][128], bf16 out -------
// Block: 64 rows x 128 cols, 256 thr = 4 waves; wave w -> rows w*16..w*16+15, all 8 n-tiles.
// mfma_f32_16x16x32_bf16: A[m=lane&15][k=(lane>>4)*8+j], B[n=lane&15][k=(lane>>4)*8+j],
// C/D: col=lane&15, row=(lane>>4)*4+reg  (guide-verified m89/m91).

__global__ __launch_bounds__(256) void k_gemm1(const float* __restrict__ x, const u16* __restrict__ wt,
                                               u16* __restrict__ h1) {
  __shared__ u16 xs[64][72];        // 64 rows x 64-K bf16, row stride 144B   (9.2 KB)
  __shared__ u16 ws[128][72];       // 128 cols x 64-K bf16 (B^T layout)      (18.4 KB)
  int t = threadIdx.x;
  int row0 = blockIdx.x * 64;
  int w = t >> 6, l = t & 63;
  int lm = l & 15, lq = l >> 4;     // col-in-tile / quad
  int mbase = w * 16;
  f32x4 acc[8];
#pragma unroll
  for (int nt = 0; nt < 8; nt++) acc[nt] = (f32x4){0.f, 0.f, 0.f, 0.f};

  for (int c = 0; c < 8; c++) {
    int k0 = c * 64;
    // stage x tile: 64 rows x 64 K, fp32 -> bf16 (1024 float4 units)
#pragma unroll
    for (int it = 0; it < 4; it++) {
      int u = t + it * 256;
      int row = u >> 4, seg = u & 15;
      int gr = row0 + row;
      float4 v = make_float4(0.f, 0.f, 0.f, 0.f);
      if (gr < NN) v = *(const float4*)&x[gr * DIN + k0 + seg * 4];
      ushort4 o;
      o.x = f2bf(v.x); o.y = f2bf(v.y); o.z = f2bf(v.z); o.w = f2bf(v.w);
      *(ushort4*)&xs[row][seg * 4] = o;
    }
    // stage W^T tile: 128 cols x 64 K bf16 (1024 x 16B units, contiguous copies)
#pragma unroll
    for (int it = 0; it < 4; it++) {
      int u = t + it * 256;
      int n = u >> 3, seg = u & 7;
      *(uint4*)&ws[n][seg * 8] = *(const uint4*)&wt[n * DIN + k0 + seg * 8];
    }
    __syncthreads();
#pragma unroll
    for (int s = 0; s < 2; s++) {
      short8 a = *(const short8*)&xs[mbase + lm][s * 32 + lq * 8];
#pragma unroll
      for (int nt = 0; nt < 8; nt++) {
        short8 b = *(const short8*)&ws[nt * 16 + lm][s * 32 + lq * 8];
        acc[nt] = __builtin_amdgcn_mfma_f32_16x16x32_bf16(a, b, acc[nt], 0, 0, 0);
      }
    }
    __syncthreads();
  }
  // epilogue: lane holds (row = lq*4+reg, col = lm) of each 16x16 tile
#pragma unroll
  for (int reg = 0; reg < 4; reg++) {
    int gr = row0 + mbase + lq * 4 + reg;
    if (gr < NN) {
#pragma unroll
      for (int nt = 0; nt < 8; nt++) {
        h1[gr * DHID + nt * 16 + lm] = f2bf(acc[nt][reg]);
      }
    }
  }
}

// ---------------- prop1: g = relu(b1 + Ahat @ h1), bf16 intermediate ----------------
// One 64-lane wave per node; halves process alternating edges, lane covers 4 feats (ushort4).

__global__ __launch_bounds__(64) void k_prop1(const u16* __restrict__ h1, const float* __restrict__ dinv,
                                              const int* __restrict__ offs, const int* __restrict__ csr,
                                              const float* __restrict__ wgt, const float* __restrict__ b1,
                                              u16* __restrict__ g) {
  int n = blockIdx.x;
  int l = threadIdx.x;
  int half = l >> 5, c = l & 31;
  int fb = c * 4;
  float dn = dinv[n];
  float ax = 0.f, ay = 0.f, az = 0.f, aw = 0.f;
  if (half == 0) {                      // self-loop: dn * h1[n] (outer dn applied at end)
    ushort4 sv = *(const ushort4*)&h1[n * DHID + fb];
    ax = dn * bf2f(sv.x); ay = dn * bf2f(sv.y); az = dn * bf2f(sv.z); aw = dn * bf2f(sv.w);
  }
  int p1e = offs[n + 1];
  int q = offs[n] + half;
  for (; q + 2 < p1e; q += 4) {         // this half handles q and q+2
    int s0 = csr[q], s1 = csr[q + 2];
    float w0 = wgt[q], w1 = wgt[q + 2];
    ushort4 v0 = *(const ushort4*)&h1[s0 * DHID + fb];
    ushort4 v1 = *(const ushort4*)&h1[s1 * DHID + fb];
    ax += w0 * bf2f(v0.x) + w1 * bf2f(v1.x);
    ay += w0 * bf2f(v0.y) + w1 * bf2f(v1.y);
    az += w0 * bf2f(v0.z) + w1 * bf2f(v1.z);
    aw += w0 * bf2f(v0.w) + w1 * bf2f(v1.w);
  }
  if (q < p1e) {                        // tail (at most one more per half)
    int s0 = csr[q];
    float w0 = wgt[q];
    ushort4 v0 = *(const ushort4*)&h1[s0 * DHID + fb];
    ax += w0 * bf2f(v0.x); ay += w0 * bf2f(v0.y);
    az += w0 * bf2f(v0.z); aw += w0 * bf2f(v0.w);
  }
  ax += __shfl_xor(ax, 32); ay += __shfl_xor(ay, 32);
  az += __shfl_xor(az, 32); aw += __shfl_xor(aw, 32);
  if (half == 0) {
    float4 bv = *(const float4*)&b1[fb];
    ushort4 o;
    o.x = f2bf(fmaxf(bv.x + dn * ax, 0.f));
    o.y = f2bf(fmaxf(bv.y + dn * ay, 0.f));
    o.z = f2bf(fmaxf(bv.z + dn * az, 0.f));
    o.w = f2bf(fmaxf(bv.w + dn * aw, 0.f));
    *(ushort4*)&g[n * DHID + fb] = o;
  }
}

// ---------------- GEMM2: h2[NN][40] = g[NN][128] @ W2[128][40] ----------------

__global__ __launch_bounds__(320) void k_gemm2(const u16* __restrict__ g, const float* __restrict__ W2,
                                               u16* __restrict__ h2) {
  __shared__ float w2s[DHID][DOUT];   // 20 KB
  __shared__ float gs[8][DHID];       // 4 KB
  int t = threadIdx.x;
  int row0 = blockIdx.x * 8;
  for (int idx = t; idx < DHID * DOUT; idx += 320) ((float*)w2s)[idx] = W2[idx];
  for (int idx = t; idx < 8 * DHID; idx += 320) {
    int r = idx >> 7, k = idx & 127;
    int gr = row0 + r;
    ((float*)gs)[idx] = (gr < NN) ? bf2f(g[gr * DHID + k]) : 0.f;
  }
  __syncthreads();
  int r = t / DOUT, c = t % DOUT;     // 8 rows x 40 cols = 320 threads exactly
  float acc = 0.f;
#pragma unroll
  for (int k = 0; k < DHID; k += 4) {
    float4 gv = *(const float4*)&gs[r][k];
    acc += gv.x * w2s[k][c] + gv.y * w2s[k + 1][c] + gv.z * w2s[k + 2][c] + gv.w * w2s[k + 3][c];
  }
  int gr = row0 + r;
  if (gr < NN) h2[gr * DOUT + c] = f2bf(acc);
}

// ---------------- prop2 + log_softmax, fp32 out ----------------

__global__ __launch_bounds__(64) void k_prop2(const u16* __restrict__ h2, const float* __restrict__ dinv,
                                              const int* __restrict__ offs, const int* __restrict__ csr,
                                              const float* __restrict__ wgt, const float* __restrict__ b2,
                                              float* __restrict__ out) {
  int n = blockIdx.x, c = threadIdx.x;
  bool act = c < DOUT;
  float dn = dinv[n];
  float accE = 0.f;
  float self = act ? (dn * bf2f(h2[n * DOUT + c])) : 0.f;
  int p = offs[n], p1 = offs[n + 1];
  for (; p + 4 <= p1; p += 4) {
    int s0 = csr[p], s1 = csr[p + 1], s2 = csr[p + 2], s3 = csr[p + 3];
    float w0 = wgt[p], w1 = wgt[p + 1], w2 = wgt[p + 2], w3 = wgt[p + 3];
    float v0 = act ? bf2f(h2[s0 * DOUT + c]) : 0.f;
    float v1 = act ? bf2f(h2[s1 * DOUT + c]) : 0.f;
    float v2 = act ? bf2f(h2[s2 * DOUT + c]) : 0.f;
    float v3 = act ? bf2f(h2[s3 * DOUT + c]) : 0.f;
    accE += w0 * v0 + w1 * v1 + w2 * v2 + w3 * v3;
  }
  for (; p < p1; p++) {
    int s0 = csr[p];
    float v0 = act ? bf2f(h2[s0 * DOUT + c]) : 0.f;
    accE += wgt[p] * v0;
  }
  float logit = act ? (b2[c] + dn * (self + accE)) : -INFINITY;
  float mx = logit;
#pragma unroll
  for (int o = 32; o > 0; o >>= 1) mx = fmaxf(mx, __shfl_xor(mx, o));
  float pv = act ? __expf(logit - mx) : 0.f;
  float sm = pv;
#pragma unroll
  for (int o = 32; o > 0; o >>= 1) sm += __shfl_xor(sm, o);
  if (act) out[n * DOUT + c] = logit - mx - logf(sm);
}

// ---------------- launch ----------------

extern "C" void kernel_launch(void* const* d_in, const int* in_sizes, int n_in,
                              void* d_out, int out_size, void* d_ws, size_t ws_size,
                              hipStream_t stream) {
  const float* x  = (const float*)d_in[0];   // fp32
  const int* ei   = (const int*)d_in[1];     // int32 on device
  const float* W1 = (const float*)d_in[2];
  const float* b1 = (const float*)d_in[3];
  const float* W2 = (const float*)d_in[4];
  const float* b2 = (const float*)d_in[5];
  float* out      = (float*)d_out;           // fp32 output

  char* ws = (char*)d_ws;
  // layout (bytes): cnt 400000 | dinv 400000 | offs 400128 | bsum 512 | csr 6400000 |
  //                 ticket 6400000 | wgt 6400000 | h1 25600000 (h2 overlays h1) | g 25600000 |
  //                 wt 131072  -> total ~71.7 MB
  int*   cnt    = (int*)(ws + 0);
  float* dinv   = (float*)(ws + 400000);
  int*   offs   = (int*)(ws + 800000);
  int*   bsum   = (int*)(ws + 1200128);
  int*   csr    = (int*)(ws + 1200640);
  int*   ticket = (int*)(ws + 7600640);
  float* wgt    = (float*)(ws + 14000640);
  u16*   h1     = (u16*)(ws + 20400640);
  u16*   h2     = (u16*)(ws + 20400640);     // overlay on h1 (h1 dead after prop1)
  u16*   g      = (u16*)(ws + 46000640);
  u16*   wt     = (u16*)(ws + 71600640);     // W1^T in bf16: [128][512]

  hipMemsetAsync(cnt, 0, 400000, stream);                    // cnt = 0

  k_count   <<<(NE / 4 + 255) / 256, 256, 0, stream>>>(ei, cnt, ticket);
  k_dinv    <<<(NN + 255) / 256, 256, 0, stream>>>(cnt, dinv);
  k_blocksum<<<NB, 256, 0, stream>>>(cnt, bsum);
  k_scanbsum<<<1, 128, 0, stream>>>(bsum);
  k_scan3   <<<NB, 256, 0, stream>>>(cnt, bsum, offs);
  k_scatter <<<(NE / 4 + 255) / 256, 256, 0, stream>>>(ei, offs, ticket, dinv, csr, wgt);

  k_prepw   <<<(DIN * DHID) / 256, 256, 0, stream>>>(W1, wt);
  k_gemm1   <<<(NN + 63) / 64, 256, 0, stream>>>(x, wt, h1);
  k_prop1   <<<NN, 64, 0, stream>>>(h1, dinv, offs, csr, wgt, b1, g);
  k_gemm2   <<<(NN + 7) / 8, 320, 0, stream>>>(g, W2, h2);
  k_prop2   <<<NN, 64, 0, stream>>>(h2, dinv, offs, csr, wgt, b2, out);
}